// Round 5
// baseline (1344.143 us; speedup 1.0000x reference)
//
#include <hip/hip_runtime.h>
#include <math.h>

// Problem constants (fixed by the reference)
#define Bdim 1024
#define DEPTHC 6

typedef __attribute__((ext_vector_type(8))) short bf16x8;
typedef __attribute__((ext_vector_type(4))) float f32x4;

__device__ __forceinline__ unsigned short f2bf(float x) {
    unsigned u = __float_as_uint(x);
    u += 0x7fffu + ((u >> 16) & 1u);
    return (unsigned short)(u >> 16);
}
__device__ __forceinline__ float bf2f(unsigned short h) {
    return __uint_as_float(((unsigned)h) << 16);
}
__device__ __forceinline__ float sigmf(float x) { return 1.0f / (1.0f + expf(-x)); }

// Preorder index of node (level, q) in a full binary tree of depth DEPTHC.
__device__ __forceinline__ int preorder_idx(int level, int q) {
    int idx = 0, rem = DEPTHC;
    for (int k = level - 1; k >= 0; --k) {
        int b = (q >> k) & 1;
        idx += 1 + b * ((1 << (rem - 1)) - 1);
        rem--;
    }
    return idx;
}

// ---------------------------------------------------------------------------
// Fragment-packed bf16x2 layout.
// Logical matrix X[R][K] (hi) + lo plane stored as K-blocks of 32:
//   fragment (rb, kb) = 64 lanes x 8 shorts, lane L = sub*16+c:
//     value = X[rb*16 + c][kb*32 + sub*8 .. +7]
//   flat short offset = ((rb*KB + kb) << 9) + (L << 3), KB = 2K/32.
// hi plane: kb = k>>5 for k in [0,K); lo plane: kb += K/32 (offset += (KB/2)<<9)
// poff: hi-plane element offset for (row R, k=col).
// ---------------------------------------------------------------------------
__device__ __forceinline__ size_t poff(size_t R, int col, int KB) {
    return (((R >> 4) * KB + (col >> 5)) << 9) + (((col >> 3) & 3) << 7)
         + ((R & 15) << 3) + (col & 7);
}

// ---------------------------------------------------------------------------
// fp32 -> packed bf16x2 converter (weights / z)
// ---------------------------------------------------------------------------
struct CvtEnt { const float* src; unsigned short* dst; int n; int klog2; };
struct CvtArgs { CvtEnt e[9]; };

__global__ __launch_bounds__(256) void cvt_pack(CvtArgs a) {
    CvtEnt E = a.e[blockIdx.y];
    const int kmask = (1 << E.klog2) - 1;
    const int KB = 1 << (E.klog2 - 4);
    const size_t lo_d = (size_t)(KB >> 1) << 9;
    for (int t = blockIdx.x * 256 + threadIdx.x; t < E.n; t += gridDim.x * 256) {
        const float x = E.src[t];
        const int r = t >> E.klog2, c = t & kmask;
        const unsigned short hi = f2bf(x);
        const size_t o = poff((size_t)r, c, KB);
        E.dst[o] = hi;
        E.dst[o + lo_d] = f2bf(x - bf2f(hi));
    }
}

// XCD-colocating bijective block swizzle (valid when total blocks % 8 == 0).
__device__ __forceinline__ void swz_grid(int& bx, int& by) {
    const int gx = gridDim.x;
    const int tot = gx * gridDim.y;
    int id = blockIdx.y * gx + blockIdx.x;
    if ((tot & 7) == 0) { const int per = tot >> 3; id = (id & 7) * per + (id >> 3); }
    bx = id % gx; by = id / gx;
}

// ---------------------------------------------------------------------------
// Generic GEMM (barrier-free, LDS-free): C = A @ W^T + bias.
// A packed [M rows], W packed [N rows]. Grid (N/128, M/128) + XCD swizzle.
// 4 waves (2x2), per-wave 64x64. 12-step bf16x2 split (K_eff = 768).
// Output row m -> node p = m>>10, arena row = (p*outStride+outOffset)*1024+(m&1023).
// Cf: fp32 row-major [*,Nf]; C2: packed bf16x2 (K=256). Either may be null.
// ---------------------------------------------------------------------------
__global__ __launch_bounds__(256, 2) void mfma_gemm(
    const unsigned short* __restrict__ A2, const unsigned short* __restrict__ W2,
    const float* __restrict__ bias, float* __restrict__ Cf, int Nf,
    unsigned short* __restrict__ C2, int outStride, int outOffset)
{
    const int tid = threadIdx.x;
    const int w = tid >> 6, lane = tid & 63;
    int bx, by; swz_grid(bx, by);
    const int col0 = bx * 128, m0 = by * 128;
    const int p = m0 >> 10;
    const int wr = w >> 1, wc = w & 1;
    const int arb0 = (m0 >> 4) + wr * 4;
    const int wrb0 = (col0 >> 4) + wc * 4;

    f32x4 acc[4][4];
    #pragma unroll
    for (int i = 0; i < 4; ++i)
        #pragma unroll
        for (int j = 0; j < 4; ++j)
            #pragma unroll
            for (int r = 0; r < 4; ++r) acc[i][j][r] = 0.f;

    #pragma unroll
    for (int s = 0; s < 12; ++s) {
        const int kaB = ((s & 3) << 1) + (((unsigned)(s - 4) < 4u) ? 8 : 0);
        const int kwB = ((s & 3) << 1) + ((s >= 8) ? 8 : 0);
        #pragma unroll
        for (int kk = 0; kk < 2; ++kk) {
            bf16x8 af[4], bw[4];
            #pragma unroll
            for (int mf = 0; mf < 4; ++mf)
                af[mf] = *(const bf16x8*)(A2 + (((size_t)(arb0 + mf) * 16 + kaB + kk) << 9) + (lane << 3));
            #pragma unroll
            for (int nf = 0; nf < 4; ++nf)
                bw[nf] = *(const bf16x8*)(W2 + (((size_t)(wrb0 + nf) * 16 + kwB + kk) << 9) + (lane << 3));
            #pragma unroll
            for (int mf = 0; mf < 4; ++mf)
                #pragma unroll
                for (int nf = 0; nf < 4; ++nf)
                    acc[mf][nf] = __builtin_amdgcn_mfma_f32_16x16x32_bf16(
                        af[mf], bw[nf], acc[mf][nf], 0, 0, 0);
        }
    }

    const size_t oBase = (((size_t)(p * outStride + outOffset)) << 10) + (m0 & 1023);
    #pragma unroll
    for (int nf = 0; nf < 4; ++nf) {
        const int col = col0 + (wc << 6) + (nf << 4) + (lane & 15);
        const float bj = bias[col];
        #pragma unroll
        for (int mf = 0; mf < 4; ++mf) {
            const int rb = (wr << 6) + (mf << 4) + ((lane >> 4) << 2);
            #pragma unroll
            for (int r = 0; r < 4; ++r) {
                const float v = acc[mf][nf][r] + bj;
                const size_t R = oBase + rb + r;
                if (Cf) Cf[R * (size_t)Nf + col] = v;
                if (C2) {
                    const unsigned short hi = f2bf(v);
                    const size_t o = poff(R, col, 16);
                    C2[o] = hi;
                    C2[o + 4096] = f2bf(v - bf2f(hi));
                }
            }
        }
    }
}

// ---------------------------------------------------------------------------
// Dual GEMM: Wcat = [ga_wh(768) | w_c_w(256)] packed, N=1024, A = hac packed.
// cols <768: GhA fp32 (+ga_bh). cols >=768: hac' fp32 + packed (+w_c_b).
// Grid (8, 8) + swizzle.
// ---------------------------------------------------------------------------
__global__ __launch_bounds__(256, 2) void mfma_gemm_dual(
    const unsigned short* __restrict__ A2, const unsigned short* __restrict__ Wcat,
    const float* __restrict__ bias_g, const float* __restrict__ bias_c,
    float* __restrict__ GhA, float* __restrict__ hacF, unsigned short* __restrict__ hac2)
{
    const int tid = threadIdx.x;
    const int w = tid >> 6, lane = tid & 63;
    int bx, by; swz_grid(bx, by);
    const int col0 = bx * 128, m0 = by * 128;
    const int wr = w >> 1, wc = w & 1;
    const int arb0 = (m0 >> 4) + wr * 4;
    const int wrb0 = (col0 >> 4) + wc * 4;

    f32x4 acc[4][4];
    #pragma unroll
    for (int i = 0; i < 4; ++i)
        #pragma unroll
        for (int j = 0; j < 4; ++j)
            #pragma unroll
            for (int r = 0; r < 4; ++r) acc[i][j][r] = 0.f;

    #pragma unroll
    for (int s = 0; s < 12; ++s) {
        const int kaB = ((s & 3) << 1) + (((unsigned)(s - 4) < 4u) ? 8 : 0);
        const int kwB = ((s & 3) << 1) + ((s >= 8) ? 8 : 0);
        #pragma unroll
        for (int kk = 0; kk < 2; ++kk) {
            bf16x8 af[4], bw[4];
            #pragma unroll
            for (int mf = 0; mf < 4; ++mf)
                af[mf] = *(const bf16x8*)(A2 + (((size_t)(arb0 + mf) * 16 + kaB + kk) << 9) + (lane << 3));
            #pragma unroll
            for (int nf = 0; nf < 4; ++nf)
                bw[nf] = *(const bf16x8*)(Wcat + (((size_t)(wrb0 + nf) * 16 + kwB + kk) << 9) + (lane << 3));
            #pragma unroll
            for (int mf = 0; mf < 4; ++mf)
                #pragma unroll
                for (int nf = 0; nf < 4; ++nf)
                    acc[mf][nf] = __builtin_amdgcn_mfma_f32_16x16x32_bf16(
                        af[mf], bw[nf], acc[mf][nf], 0, 0, 0);
        }
    }

    #pragma unroll
    for (int nf = 0; nf < 4; ++nf) {
        const int col = col0 + (wc << 6) + (nf << 4) + (lane & 15);
        #pragma unroll
        for (int mf = 0; mf < 4; ++mf) {
            const int rb = m0 + (wr << 6) + (mf << 4) + ((lane >> 4) << 2);
            #pragma unroll
            for (int r = 0; r < 4; ++r) {
                const size_t R = rb + r;
                if (col < 768) {
                    GhA[R * 768 + col] = acc[mf][nf][r] + bias_g[col];
                } else {
                    const int c = col - 768;
                    const float v = acc[mf][nf][r] + bias_c[c];
                    hacF[R * 256 + c] = v;
                    const unsigned short hi = f2bf(v);
                    const size_t o = poff(R, c, 16);
                    hac2[o] = hi;
                    hac2[o + 4096] = f2bf(v - bf2f(hi));
                }
            }
        }
    }
}

// ---------------------------------------------------------------------------
// pred = H @ h2o^T + b (packed fragments direct from global), scatter to out
// at preorder index; softmax -> SP2 (packed bf16x2, logical K=32).
// Block: 64 rows of one node (16 stripes/node), 4 waves x 16 rows. Grid M/64.
// ---------------------------------------------------------------------------
__global__ __launch_bounds__(256) void pred_softmax_p(
    const unsigned short* __restrict__ A2, const unsigned short* __restrict__ h2o2,
    const float* __restrict__ h2o_b, float* __restrict__ out,
    unsigned short* __restrict__ SP2, int level, int nodeStride, int nodeOffset)
{
    const int tid = threadIdx.x;
    const int w = tid >> 6, lane = tid & 63;
    const int stripe = blockIdx.x;
    const int p = stripe >> 4;
    const int q = p * nodeStride + nodeOffset;
    const int b0 = (stripe & 15) * 64;
    const int rbA = (((q << 10) + b0) >> 4) + w;

    f32x4 acc[2];
    #pragma unroll
    for (int j = 0; j < 2; ++j)
        #pragma unroll
        for (int r = 0; r < 4; ++r) acc[j][r] = 0.f;

    #pragma unroll
    for (int s = 0; s < 12; ++s) {
        const int kaB = ((s & 3) << 1) + (((unsigned)(s - 4) < 4u) ? 8 : 0);
        const int kwB = ((s & 3) << 1) + ((s >= 8) ? 8 : 0);
        #pragma unroll
        for (int kk = 0; kk < 2; ++kk) {
            const bf16x8 af = *(const bf16x8*)(A2 + (((size_t)rbA * 16 + kaB + kk) << 9) + (lane << 3));
            #pragma unroll
            for (int nf = 0; nf < 2; ++nf) {
                const bf16x8 bw = *(const bf16x8*)(h2o2 + (((size_t)nf * 16 + kwB + kk) << 9) + (lane << 3));
                acc[nf] = __builtin_amdgcn_mfma_f32_16x16x32_bf16(af, bw, acc[nf], 0, 0, 0);
            }
        }
    }

    const int idx = preorder_idx(level, q);
    const float bj0 = h2o_b[(lane & 15)];
    const float bj1 = h2o_b[16 + (lane & 15)];

    #pragma unroll
    for (int r = 0; r < 4; ++r) {
        const int b = b0 + (w << 4) + ((lane >> 4) << 2) + r;
        const float v0 = acc[0][r] + bj0;
        const float v1 = acc[1][r] + bj1;
        const size_t obase = (((size_t)idx << 10) + b) * 32;
        out[obase + (lane & 15)] = v0;
        out[obase + 16 + (lane & 15)] = v1;
        float mx = fmaxf(v0, v1);
        #pragma unroll
        for (int off = 8; off > 0; off >>= 1) mx = fmaxf(mx, __shfl_xor(mx, off, 64));
        const float e0 = expf(v0 - mx), e1 = expf(v1 - mx);
        float sum = e0 + e1;
        #pragma unroll
        for (int off = 8; off > 0; off >>= 1) sum += __shfl_xor(sum, off, 64);
        const float inv = 1.0f / sum;
        const float s0 = e0 * inv, s1 = e1 * inv;
        const size_t R = ((size_t)q << 10) + b;
        const int j0 = lane & 15;
        const unsigned short h0 = f2bf(s0), h1 = f2bf(s1);
        const size_t o0 = poff(R, j0, 2);
        const size_t o1 = poff(R, j0 + 16, 2);
        SP2[o0] = h0;         SP2[o0 + 512] = f2bf(s0 - bf2f(h0));
        SP2[o1] = h1;         SP2[o1 + 512] = f2bf(s1 - bf2f(h1));
    }
}

// ---------------------------------------------------------------------------
// Ancestral GRU (VALU): Ap[m,j] = (1-z)*n + z*ha[b,j]; x-dots K=32 from
// packed SP2c (hi+lo reconstruct); h-parts from GhA. 16 rows x 256 cols/block.
// ---------------------------------------------------------------------------
__global__ __launch_bounds__(256) void gru_a_kernel(
    const unsigned short* __restrict__ SP2c, const float* __restrict__ GhA,
    const float* __restrict__ wx, const float* __restrict__ bx,
    const float* __restrict__ ha, float* __restrict__ Apart)
{
    __shared__ float sps[16][33];
    const int tid = threadIdx.x;
    const int m0  = blockIdx.x * 16;

    for (int t = tid; t < 16 * 32; t += 256) {
        const int r = t >> 5, k = t & 31;
        const size_t o = poff((size_t)(m0 + r), k, 2);
        sps[r][k] = bf2f(SP2c[o]) + bf2f(SP2c[o + 512]);
    }
    __syncthreads();

    const int j = tid;
    float accr[16] = {}, accz[16] = {}, accn[16] = {};
    const float* wxj = wx + (size_t)j * 32;
    for (int k = 0; k < 32; ++k) {
        const float wr_ = wxj[k];
        const float wz_ = wxj[8192 + k];
        const float wn_ = wxj[16384 + k];
        #pragma unroll
        for (int r = 0; r < 16; ++r) {
            const float s = sps[r][k];
            accr[r] = fmaf(s, wr_, accr[r]);
            accz[r] = fmaf(s, wz_, accz[r]);
            accn[r] = fmaf(s, wn_, accn[r]);
        }
    }
    const float bxr = bx[j], bxz = bx[256 + j], bxn = bx[512 + j];
    #pragma unroll
    for (int r = 0; r < 16; ++r) {
        const int m = m0 + r;
        const int b = m & 1023;
        const float ghr = GhA[(size_t)b * 768 + j];
        const float ghz = GhA[(size_t)b * 768 + 256 + j];
        const float ghn = GhA[(size_t)b * 768 + 512 + j];
        const float rg = sigmf(accr[r] + bxr + ghr);
        const float zg = sigmf(accz[r] + bxz + ghz);
        const float ng = tanhf(accn[r] + bxn + rg * ghn);
        Apart[(size_t)m * 256 + j] = (1.f - zg) * ng + zg * ha[(size_t)b * 256 + j];
    }
}

// ---------------------------------------------------------------------------
// Fraternal GRU (barrier-free, LDS-free): h = first-child hidden (packed,
// slots 2p), x = first-child softmax (packed K=32). 12 h-steps + 2 x-ksteps.
// Grid (4, M/128) + swizzle; 4 waves (2x2): per-wave 64 rows x 32 cols x 3 gates.
// Epilogue: gates + add Apf, write hidden2 packed into Ap2 (compact rows).
// ---------------------------------------------------------------------------
__global__ __launch_bounds__(256, 2) void gru_s_p(
    const unsigned short* __restrict__ Hn2, const unsigned short* __restrict__ SP2n,
    const unsigned short* __restrict__ gsW2, const unsigned short* __restrict__ gsX2,
    const float* __restrict__ gs_bx, const float* __restrict__ gs_bh,
    const float* __restrict__ Apf, unsigned short* __restrict__ Ap2)
{
    const int tid = threadIdx.x;
    const int w = tid >> 6, lane = tid & 63;
    int bx, by; swz_grid(bx, by);
    const int col0 = bx * 64;
    const int m0 = by * 128;
    const int p = m0 >> 10;
    const size_t aBase = (((size_t)(2 * p)) << 10) + (m0 & 1023);
    const int wr = w >> 1, wc = w & 1;
    const int arb0 = (int)(aBase >> 4) + wr * 4;
    const int cb0 = (col0 >> 4) + wc * 2;   // + g*16 + nf

    f32x4 a_r[4][2], a_z[4][2], a_nh[4][2], a_nx[4][2];
    #pragma unroll
    for (int i = 0; i < 4; ++i)
        #pragma unroll
        for (int j = 0; j < 2; ++j)
            #pragma unroll
            for (int r = 0; r < 4; ++r) {
                a_r[i][j][r] = 0.f; a_z[i][j][r] = 0.f;
                a_nh[i][j][r] = 0.f; a_nx[i][j][r] = 0.f;
            }

    #pragma unroll
    for (int s = 0; s < 12; ++s) {
        const int kaB = ((s & 3) << 1) + (((unsigned)(s - 4) < 4u) ? 8 : 0);
        const int kwB = ((s & 3) << 1) + ((s >= 8) ? 8 : 0);
        #pragma unroll
        for (int kk = 0; kk < 2; ++kk) {
            bf16x8 af[4], bw[3][2];
            #pragma unroll
            for (int mf = 0; mf < 4; ++mf)
                af[mf] = *(const bf16x8*)(Hn2 + (((size_t)(arb0 + mf) * 16 + kaB + kk) << 9) + (lane << 3));
            #pragma unroll
            for (int g = 0; g < 3; ++g)
                #pragma unroll
                for (int nf = 0; nf < 2; ++nf)
                    bw[g][nf] = *(const bf16x8*)(gsW2 + (((size_t)(g * 16 + cb0 + nf) * 16 + kwB + kk) << 9) + (lane << 3));
            #pragma unroll
            for (int mf = 0; mf < 4; ++mf)
                #pragma unroll
                for (int nf = 0; nf < 2; ++nf) {
                    a_r[mf][nf]  = __builtin_amdgcn_mfma_f32_16x16x32_bf16(af[mf], bw[0][nf], a_r[mf][nf], 0, 0, 0);
                    a_z[mf][nf]  = __builtin_amdgcn_mfma_f32_16x16x32_bf16(af[mf], bw[1][nf], a_z[mf][nf], 0, 0, 0);
                    a_nh[mf][nf] = __builtin_amdgcn_mfma_f32_16x16x32_bf16(af[mf], bw[2][nf], a_nh[mf][nf], 0, 0, 0);
                }
        }
    }

    // x-path: logical K=32 -> 2 packed k-blocks (hi, lo)
    #pragma unroll
    for (int kk = 0; kk < 2; ++kk) {
        bf16x8 af[4], bw[3][2];
        #pragma unroll
        for (int mf = 0; mf < 4; ++mf)
            af[mf] = *(const bf16x8*)(SP2n + (((size_t)(arb0 + mf) * 2 + kk) << 9) + (lane << 3));
        #pragma unroll
        for (int g = 0; g < 3; ++g)
            #pragma unroll
            for (int nf = 0; nf < 2; ++nf)
                bw[g][nf] = *(const bf16x8*)(gsX2 + (((size_t)(g * 16 + cb0 + nf) * 2 + kk) << 9) + (lane << 3));
        #pragma unroll
        for (int mf = 0; mf < 4; ++mf)
            #pragma unroll
            for (int nf = 0; nf < 2; ++nf) {
                a_r[mf][nf]  = __builtin_amdgcn_mfma_f32_16x16x32_bf16(af[mf], bw[0][nf], a_r[mf][nf], 0, 0, 0);
                a_z[mf][nf]  = __builtin_amdgcn_mfma_f32_16x16x32_bf16(af[mf], bw[1][nf], a_z[mf][nf], 0, 0, 0);
                a_nx[mf][nf] = __builtin_amdgcn_mfma_f32_16x16x32_bf16(af[mf], bw[2][nf], a_nx[mf][nf], 0, 0, 0);
            }
    }

    #pragma unroll
    for (int nf = 0; nf < 2; ++nf) {
        const int jc = col0 + (wc << 5) + (nf << 4) + (lane & 15);
        const float bsr  = gs_bx[jc] + gs_bh[jc];
        const float bsz  = gs_bx[256 + jc] + gs_bh[256 + jc];
        const float bsnx = gs_bx[512 + jc];
        const float bsnh = gs_bh[512 + jc];
        #pragma unroll
        for (int mf = 0; mf < 4; ++mf) {
            #pragma unroll
            for (int r = 0; r < 4; ++r) {
                const int rowl = (wr << 6) + (mf << 4) + ((lane >> 4) << 2) + r;
                const size_t m = (size_t)(m0 + rowl);
                const float rs = sigmf(a_r[mf][nf][r] + bsr);
                const float zs = sigmf(a_z[mf][nf][r] + bsz);
                const float ns = tanhf(a_nx[mf][nf][r] + bsnx + rs * (a_nh[mf][nf][r] + bsnh));
                const size_t Rh = aBase + rowl;
                const size_t oh = poff(Rh, jc, 16);
                const float hv = bf2f(Hn2[oh]) + bf2f(Hn2[oh + 4096]);
                const float val = (1.f - zs) * ns + zs * hv + Apf[m * 256 + jc];
                const unsigned short hi = f2bf(val);
                const size_t oo = poff(m, jc, 16);
                Ap2[oo] = hi;
                Ap2[oo + 4096] = f2bf(val - bf2f(hi));
            }
        }
    }
}

// ---------------------------------------------------------------------------
extern "C" void kernel_launch(void* const* d_in, const int* in_sizes, int n_in,
                              void* d_out, int out_size, void* d_ws, size_t ws_size,
                              hipStream_t stream) {
    (void)in_sizes; (void)n_in; (void)out_size;

    const float* z      = (const float*)d_in[0];
    const float* h2o_w  = (const float*)d_in[1];
    const float* h2o_b  = (const float*)d_in[2];
    const float* w_c_w  = (const float*)d_in[3];
    const float* w_c_b  = (const float*)d_in[4];
    const float* w_d_w  = (const float*)d_in[5];
    const float* w_d_b  = (const float*)d_in[6];
    const float* z2h1_w = (const float*)d_in[7];
    const float* z2h1_b = (const float*)d_in[8];
    const float* z2h2_w = (const float*)d_in[9];
    const float* z2h2_b = (const float*)d_in[10];
    const float* ga_wx  = (const float*)d_in[11];
    const float* ga_wh  = (const float*)d_in[12];
    const float* ga_bx  = (const float*)d_in[13];
    const float* ga_bh  = (const float*)d_in[14];
    const float* gs_wx  = (const float*)d_in[15];
    const float* gs_wh  = (const float*)d_in[16];
    const float* gs_bx  = (const float*)d_in[17];
    const float* gs_bh  = (const float*)d_in[18];

    float* out = (float*)d_out;

    size_t off = 0;
    auto alloc = [&](size_t bytes) -> void* {
        void* r = (char*)d_ws + off;
        off += (bytes + 255) & ~(size_t)255;
        return r;
    };
    unsigned short* H2a  = (unsigned short*)alloc(16ull * 1024 * 512 * 2);
    unsigned short* H2b  = (unsigned short*)alloc(32ull * 1024 * 512 * 2);
    unsigned short* SP2a = (unsigned short*)alloc(16ull * 1024 * 64 * 2);
    unsigned short* SP2b = (unsigned short*)alloc(32ull * 1024 * 64 * 2);
    float* hacF0 = (float*)alloc(1024ull * 256 * 4);
    float* hacF1 = (float*)alloc(1024ull * 256 * 4);
    unsigned short* hac20 = (unsigned short*)alloc(1024ull * 512 * 2);
    unsigned short* hac21 = (unsigned short*)alloc(1024ull * 512 * 2);
    float* GhA = (float*)alloc(1024ull * 768 * 4);
    float* Apf = (float*)alloc(16ull * 1024 * 256 * 4);
    unsigned short* Ap2 = (unsigned short*)alloc(16ull * 1024 * 512 * 2);
    unsigned short* z2  = (unsigned short*)alloc(1024ull * 512 * 2);
    unsigned short* wd2 = (unsigned short*)alloc(256ull * 512 * 2);
    unsigned short* wcat = (unsigned short*)alloc(1024ull * 512 * 2);  // [ga_wh(768)|w_c_w(256)] packed
    unsigned short* gaW2 = wcat;
    unsigned short* wc2  = wcat + 768ull * 512;   // row-block 48 onward
    unsigned short* z12 = (unsigned short*)alloc(256ull * 512 * 2);
    unsigned short* z22 = (unsigned short*)alloc(256ull * 512 * 2);
    unsigned short* gsW2 = (unsigned short*)alloc(768ull * 512 * 2);
    unsigned short* gsX2 = (unsigned short*)alloc(768ull * 64 * 2);
    unsigned short* h2o2 = (unsigned short*)alloc(32ull * 512 * 2);
    if (off > ws_size) return;  // tripwire: output stays poisoned -> visible fail

    const dim3 blk(256);

    CvtArgs ca = {{
        { z,      z2,   1024 * 256, 8 },
        { w_d_w,  wd2,  256 * 256,  8 },
        { w_c_w,  wc2,  256 * 256,  8 },
        { z2h1_w, z12,  256 * 256,  8 },
        { z2h2_w, z22,  256 * 256,  8 },
        { ga_wh,  gaW2, 768 * 256,  8 },
        { gs_wh,  gsW2, 768 * 256,  8 },
        { gs_wx,  gsX2, 768 * 32,   5 },
        { h2o_w,  h2o2, 32 * 256,   8 },
    }};
    cvt_pack<<<dim3(64, 9), blk, 0, stream>>>(ca);

    // init: hac = z@z2h1^T+b ; H(root) = z@z2h2^T+b ; root pred+softmax
    mfma_gemm<<<dim3(2, 8), blk, 0, stream>>>(z2, z12, z2h1_b, hacF0, 256, hac20, 1, 0);
    mfma_gemm<<<dim3(2, 8), blk, 0, stream>>>(z2, z22, z2h2_b, nullptr, 0, H2a, 1, 0);
    pred_softmax_p<<<dim3(16), blk, 0, stream>>>(H2a, h2o2, h2o_b, out, SP2a, 0, 1, 0);

    unsigned short* cur2 = H2a;  unsigned short* nxt2 = H2b;
    unsigned short* spc  = SP2a; unsigned short* spn  = SP2b;
    float* hf = hacF0;  float* hn = hacF1;
    unsigned short* hf2 = hac20; unsigned short* hn2 = hac21;

    for (int l = 0; l < DEPTHC - 1; ++l) {
        const int M = (1 << l) * Bdim;

        // first children: H' = lin_d(H) -> slots 2p
        mfma_gemm<<<dim3(2, M / 128), blk, 0, stream>>>(cur2, wd2, w_d_b, nullptr, 0, nxt2, 2, 0);
        // pred + softmax of first children
        pred_softmax_p<<<dim3(M / 64), blk, 0, stream>>>(nxt2, h2o2, h2o_b, out, spn, l + 1, 2, 0);
        // GhA = hac@ga_wh^T + ga_bh  AND  hac' = lin_c(hac), one dual dispatch
        mfma_gemm_dual<<<dim3(8, 8), blk, 0, stream>>>(hf2, wcat, ga_bh, w_c_b, GhA, hn, hn2);
        // ancestral GRU: Apf = gru_a(sp_parent, hac)
        gru_a_kernel<<<dim3(M / 16), blk, 0, stream>>>(spc, GhA, ga_wx, ga_bx, hf, Apf);
        // fraternal GRU on first children + combine -> hidden2 (packed) in Ap2
        gru_s_p<<<dim3(4, M / 128), blk, 0, stream>>>(
            nxt2, spn, gsW2, gsX2, gs_bx, gs_bh, Apf, Ap2);
        // second children: H'' = lin_d(hidden2) -> slots 2p+1
        mfma_gemm<<<dim3(2, M / 128), blk, 0, stream>>>(Ap2, wd2, w_d_b, nullptr, 0, nxt2, 2, 1);
        // pred + softmax of second children
        pred_softmax_p<<<dim3(M / 64), blk, 0, stream>>>(nxt2, h2o2, h2o_b, out, spn, l + 1, 2, 1);

        // swap ping-pong buffers
        unsigned short* t2;
        t2 = cur2; cur2 = nxt2; nxt2 = t2;
        t2 = spc;  spc  = spn;  spn  = t2;
        float* tf = hf; hf = hn; hn = tf;
        t2 = hf2; hf2 = hn2; hn2 = t2;
    }
}

// Round 6
// 799.905 us; speedup vs baseline: 1.6804x; 1.6804x over previous
//
#include <hip/hip_runtime.h>
#include <math.h>

// Problem constants (fixed by the reference)
#define Bdim 1024
#define DEPTHC 6

typedef __attribute__((ext_vector_type(8))) short bf16x8;
typedef __attribute__((ext_vector_type(4))) float f32x4;

__device__ __forceinline__ unsigned short f2bf(float x) {
    unsigned u = __float_as_uint(x);
    u += 0x7fffu + ((u >> 16) & 1u);
    return (unsigned short)(u >> 16);
}
__device__ __forceinline__ float bf2f(unsigned short h) {
    return __uint_as_float(((unsigned)h) << 16);
}
__device__ __forceinline__ float sigmf(float x) { return 1.0f / (1.0f + expf(-x)); }

__device__ __forceinline__ void glds16(const void* g, void* l) {
    __builtin_amdgcn_global_load_lds(
        (const __attribute__((address_space(1))) unsigned int*)g,
        (__attribute__((address_space(3))) unsigned int*)l, 16, 0, 0);
}

// raw barrier (no implicit vmcnt drain) + counted vmcnt waits
__device__ __forceinline__ void sbar() { asm volatile("s_barrier" ::: "memory"); }
template<int N> __device__ __forceinline__ void vmwait() {
    static_assert(N == 0 || N == 6 || N == 8 || N == 10, "unsupported vmcnt");
    if constexpr (N == 0)  asm volatile("s_waitcnt vmcnt(0)" ::: "memory");
    if constexpr (N == 6)  asm volatile("s_waitcnt vmcnt(6)" ::: "memory");
    if constexpr (N == 8)  asm volatile("s_waitcnt vmcnt(8)" ::: "memory");
    if constexpr (N == 10) asm volatile("s_waitcnt vmcnt(10)" ::: "memory");
    __builtin_amdgcn_sched_barrier(0);
}

// Preorder index of node (level, q) in a full binary tree of depth DEPTHC.
__device__ __forceinline__ int preorder_idx(int level, int q) {
    int idx = 0, rem = DEPTHC;
    for (int k = level - 1; k >= 0; --k) {
        int b = (q >> k) & 1;
        idx += 1 + b * ((1 << (rem - 1)) - 1);
        rem--;
    }
    return idx;
}

// ---------------------------------------------------------------------------
// fp32 -> bf16x2 split converter: dst[r][0:k]=hi, dst[r][k:2k]=lo
// ---------------------------------------------------------------------------
struct CvtEnt { const float* src; unsigned short* dst; int n; int klog2; };
struct CvtArgs { CvtEnt e[8]; };

__global__ __launch_bounds__(256) void cvt_bf16x2(CvtArgs a) {
    CvtEnt E = a.e[blockIdx.y];
    const int k = 1 << E.klog2;
    for (int t = blockIdx.x * 256 + threadIdx.x; t < E.n; t += gridDim.x * 256) {
        const float x = E.src[t];
        const int r = t >> E.klog2, c = t & (k - 1);
        const unsigned short hi = f2bf(x);
        unsigned short* d = E.dst + ((size_t)r << (E.klog2 + 1));
        d[c] = hi;
        d[k + c] = f2bf(x - bf2f(hi));
    }
}

// ---------------------------------------------------------------------------
// Generic bf16x2 MFMA GEMM: C = A @ W^T + bias, logical K=256, stored K=512
// (hi|lo). 12-step schedule (hi*hi, lo*hi, hi*lo; K_eff=768).
// Tile BM x 128, BK=64, 4 waves. Counted-vmcnt double-buffered pipeline.
// Output row m -> node p=m>>10, out row = (p*outStride+outOffset)*1024+(m&1023).
// ---------------------------------------------------------------------------
template<int BM>
__global__ __launch_bounds__(256) void mfma_gemm(
    const unsigned short* __restrict__ A2, const unsigned short* __restrict__ W2,
    const float* __restrict__ bias, float* __restrict__ Cf, int Nf,
    unsigned short* __restrict__ C2, int outStride, int outOffset)
{
    constexpr int MF = BM / 32;   // A-frags per wave
    constexpr int AI = BM / 32;   // A glds per wave per step
    __shared__ __attribute__((aligned(16))) unsigned short As[2][BM * 64];
    __shared__ __attribute__((aligned(16))) unsigned short Ws[2][8192];

    const int tid = threadIdx.x;
    const int w = tid >> 6, lane = tid & 63;
    const int m0 = blockIdx.x * BM, col0 = blockIdx.y * 128;
    const int p = m0 >> 10;
    const int wm = (w >> 1) * (BM / 2), wn = (w & 1) << 6;

    f32x4 acc[MF][4] = {};

    auto stage = [&](int buf, int s) {
        const int ka = ((s & 3) << 6) + (((unsigned)(s - 4) < 4u) ? 256 : 0);
        const int kw = ((s & 3) << 6) + ((s >= 8) ? 256 : 0);
        #pragma unroll
        for (int i = 0; i < AI; ++i) {
            const int r = w * (BM / 4) + (i << 3) + (lane >> 3);
            const int sl = (lane & 7) ^ (r & 7);
            glds16(A2 + (size_t)(m0 + r) * 512 + ka + (sl << 3),
                   &As[buf][(w * (BM / 4) + (i << 3)) << 6]);
        }
        #pragma unroll
        for (int i = 0; i < 4; ++i) {
            const int r = (w << 5) + (i << 3) + (lane >> 3);
            const int sl = (lane & 7) ^ (r & 7);
            glds16(W2 + (size_t)(col0 + r) * 512 + kw + (sl << 3),
                   &Ws[buf][(w << 11) + (i << 9)]);
        }
    };
    auto compute = [&](int buf) {
        #pragma unroll
        for (int kk = 0; kk < 2; ++kk) {
            bf16x8 af[MF], bw[4];
            #pragma unroll
            for (int mf = 0; mf < MF; ++mf) {
                const int row = wm + (mf << 4) + (lane & 15);
                const int sl = (((kk << 2) | (lane >> 4)) ^ (row & 7)) << 3;
                af[mf] = *(const bf16x8*)&As[buf][(row << 6) + sl];
            }
            #pragma unroll
            for (int nf = 0; nf < 4; ++nf) {
                const int row = wn + (nf << 4) + (lane & 15);
                const int sl = (((kk << 2) | (lane >> 4)) ^ (row & 7)) << 3;
                bw[nf] = *(const bf16x8*)&Ws[buf][(row << 6) + sl];
            }
            __builtin_amdgcn_s_setprio(1);
            #pragma unroll
            for (int mf = 0; mf < MF; ++mf)
                #pragma unroll
                for (int nf = 0; nf < 4; ++nf)
                    acc[mf][nf] = __builtin_amdgcn_mfma_f32_16x16x32_bf16(
                        af[mf], bw[nf], acc[mf][nf], 0, 0, 0);
            __builtin_amdgcn_s_setprio(0);
        }
    };

    stage(0, 0);
    #pragma unroll
    for (int s = 0; s < 12; ++s) {
        if (s + 1 < 12) { stage((s + 1) & 1, s + 1); vmwait<AI + 4>(); }
        else            { vmwait<0>(); }
        sbar();
        compute(s & 1);
        sbar();
    }

    const size_t oBase = (((size_t)(p * outStride + outOffset)) << 10) + (m0 & 1023);
    #pragma unroll
    for (int nf = 0; nf < 4; ++nf) {
        const int col = col0 + wn + (nf << 4) + (lane & 15);
        const float bj = bias[col];
        #pragma unroll
        for (int mf = 0; mf < MF; ++mf) {
            const int rb = wm + (mf << 4) + ((lane >> 4) << 2);
            #pragma unroll
            for (int r = 0; r < 4; ++r) {
                const float v = acc[mf][nf][r] + bj;
                const size_t orow = oBase + rb + r;
                if (Cf) Cf[orow * (size_t)Nf + col] = v;
                if (C2) {
                    const unsigned short hi = f2bf(v);
                    C2[orow * 512 + col] = hi;
                    C2[orow * 512 + 256 + col] = f2bf(v - bf2f(hi));
                }
            }
        }
    }
}

// ---------------------------------------------------------------------------
// pred = H @ h2o_w^T + h2o_b -> scatter to out at preorder index;
// sp = softmax(pred) -> SP2 (bf16x2, [slot*1024+b][64]).
// H read from bf16x2 arena (hi+lo reconstruct). 256 thr = 8 rows x 32 cols.
// ---------------------------------------------------------------------------
__global__ __launch_bounds__(256) void pred_softmax(
    const unsigned short* __restrict__ H2, const float* __restrict__ h2o_w,
    const float* __restrict__ h2o_b, float* __restrict__ out,
    unsigned short* __restrict__ SP2, int level, int nodeStride, int nodeOffset)
{
    __shared__ float wsm[32][260];
    __shared__ float hsm[8][260];

    const int tid = threadIdx.x;
    const int p   = blockIdx.x >> 7;
    const int b0  = (blockIdx.x & 127) * 8;
    const int q   = p * nodeStride + nodeOffset;
    const unsigned short* Hrow = H2 + ((size_t)q * Bdim + b0) * 512;

    for (int t = tid * 4; t < 32 * 256; t += 1024) {
        const float4 v = *(const float4*)(h2o_w + t);
        const int j = t >> 8, k = t & 255;
        wsm[j][k] = v.x; wsm[j][k + 1] = v.y; wsm[j][k + 2] = v.z; wsm[j][k + 3] = v.w;
    }
    for (int t = tid * 4; t < 8 * 256; t += 1024) {
        const int r = t >> 8, k = t & 255;
        const ushort4 hi4 = *(const ushort4*)(Hrow + (size_t)r * 512 + k);
        const ushort4 lo4 = *(const ushort4*)(Hrow + (size_t)r * 512 + 256 + k);
        hsm[r][k + 0] = bf2f(hi4.x) + bf2f(lo4.x);
        hsm[r][k + 1] = bf2f(hi4.y) + bf2f(lo4.y);
        hsm[r][k + 2] = bf2f(hi4.z) + bf2f(lo4.z);
        hsm[r][k + 3] = bf2f(hi4.w) + bf2f(lo4.w);
    }
    __syncthreads();

    const int r = tid >> 5;
    const int j = tid & 31;
    float acc = 0.f;
    #pragma unroll 4
    for (int k = 0; k < 256; k += 4) {
        const float4 hv = *(const float4*)&hsm[r][k];
        const float4 wv = *(const float4*)&wsm[j][k];
        acc = fmaf(hv.x, wv.x, acc);
        acc = fmaf(hv.y, wv.y, acc);
        acc = fmaf(hv.z, wv.z, acc);
        acc = fmaf(hv.w, wv.w, acc);
    }
    acc += h2o_b[j];

    const int idx = preorder_idx(level, q);
    const int b   = b0 + r;
    out[((size_t)idx * Bdim + b) * 32 + j] = acc;

    float mx = acc;
    #pragma unroll
    for (int off = 16; off > 0; off >>= 1) mx = fmaxf(mx, __shfl_xor(mx, off, 32));
    const float e = expf(acc - mx);
    float sum = e;
    #pragma unroll
    for (int off = 16; off > 0; off >>= 1) sum += __shfl_xor(sum, off, 32);
    const float sp = e / sum;

    const size_t sbase = ((size_t)q * Bdim + b) * 64;
    const unsigned short hi = f2bf(sp);
    SP2[sbase + j] = hi;
    SP2[sbase + 32 + j] = f2bf(sp - bf2f(hi));
}

// ---------------------------------------------------------------------------
// Ancestral GRU (per-node x-part + shared h-part GhA): Ap[m,j] = (1-z)*n + z*ha
// SP2c: parents' softmax (bf16x2). 16 rows x 256 cols per block.
// ---------------------------------------------------------------------------
__global__ __launch_bounds__(256) void gru_a_kernel(
    const unsigned short* __restrict__ SP2c, const float* __restrict__ GhA,
    const float* __restrict__ wx, const float* __restrict__ bx,
    const float* __restrict__ ha, float* __restrict__ Apart)
{
    __shared__ float sps[16][33];
    const int tid = threadIdx.x;
    const int m0  = blockIdx.x * 16;

    for (int t = tid; t < 16 * 32; t += 256) {
        const int r = t >> 5, k = t & 31;
        const size_t base = ((size_t)(m0 + r)) * 64;
        sps[r][k] = bf2f(SP2c[base + k]) + bf2f(SP2c[base + 32 + k]);
    }
    __syncthreads();

    const int j = tid;
    float accr[16] = {}, accz[16] = {}, accn[16] = {};
    const float* wxj = wx + (size_t)j * 32;
    for (int k = 0; k < 32; ++k) {
        const float wr_ = wxj[k];
        const float wz_ = wxj[8192 + k];
        const float wn_ = wxj[16384 + k];
        #pragma unroll
        for (int r = 0; r < 16; ++r) {
            const float s = sps[r][k];
            accr[r] = fmaf(s, wr_, accr[r]);
            accz[r] = fmaf(s, wz_, accz[r]);
            accn[r] = fmaf(s, wn_, accn[r]);
        }
    }
    const float bxr = bx[j], bxz = bx[256 + j], bxn = bx[512 + j];
    #pragma unroll
    for (int r = 0; r < 16; ++r) {
        const int m = m0 + r;
        const int b = m & 1023;
        const float ghr = GhA[(size_t)b * 768 + j];
        const float ghz = GhA[(size_t)b * 768 + 256 + j];
        const float ghn = GhA[(size_t)b * 768 + 512 + j];
        const float rg = sigmf(accr[r] + bxr + ghr);
        const float zg = sigmf(accz[r] + bxz + ghz);
        const float ng = tanhf(accn[r] + bxn + rg * ghn);
        Apart[(size_t)m * 256 + j] = (1.f - zg) * ng + zg * ha[(size_t)b * 256 + j];
    }
}

// ---------------------------------------------------------------------------
// Fraternal GRU fused MFMA: h = first-child hidden (bf16x2, slots 2p),
// x = first-child softmax. 3 gates on a 64-col slab. Tile BM x (64x3 gates).
// 12 h-steps (K_eff=768) + 1 x-step; counted-vmcnt dbuf pipeline.
// Epilogue: gates + add Apf (gru_a output), write bf16x2 hidden2 into Ap2.
// ---------------------------------------------------------------------------
template<int BM>
__global__ __launch_bounds__(256) void gru_s_fused(
    const unsigned short* __restrict__ Hn2,   // l+1 arena (first children, slots 2p)
    const unsigned short* __restrict__ SP2n,  // l+1 SP arena (slots 2p)
    const unsigned short* __restrict__ gsW2, const unsigned short* __restrict__ gsX2,
    const float* __restrict__ gs_bx, const float* __restrict__ gs_bh,
    const float* __restrict__ Apf, unsigned short* __restrict__ Ap2)
{
    constexpr int MF = BM / 32;
    constexpr int AI = BM / 32;
    __shared__ __attribute__((aligned(16))) unsigned short As[2][BM * 64];
    __shared__ __attribute__((aligned(16))) unsigned short Ws[2][12288];  // 192x64

    const int tid = threadIdx.x;
    const int w = tid >> 6, lane = tid & 63;
    const int col0 = blockIdx.y * 64;
    const int m0 = blockIdx.x * BM;
    const int p = m0 >> 10;
    const size_t aBase = (((size_t)(2 * p)) << 10) + (m0 & 1023);
    const int wr = w >> 1, wc = w & 1;

    f32x4 a_sr[MF][2] = {}, a_sz[MF][2] = {}, a_snh[MF][2] = {}, a_snx[MF][2] = {};

    auto stage = [&](int buf, int s) {
        #pragma unroll
        for (int i = 0; i < AI; ++i) {
            const int r = w * (BM / 4) + (i << 3) + (lane >> 3);
            const int sl = (lane & 7) ^ (r & 7);
            const unsigned short* src;
            if (s < 12) {
                const int ka = ((s & 3) << 6) + (((unsigned)(s - 4) < 4u) ? 256 : 0);
                src = Hn2 + (aBase + r) * 512 + ka + (sl << 3);
            } else {
                src = SP2n + (aBase + r) * 64 + (sl << 3);
            }
            glds16(src, &As[buf][(w * (BM / 4) + (i << 3)) << 6]);
        }
        #pragma unroll
        for (int j = 0; j < 6; ++j) {
            const int R = w * 48 + (j << 3) + (lane >> 3);
            const int g = R >> 6, c = R & 63;
            const int sl = (lane & 7) ^ (R & 7);
            const size_t grow = (size_t)(g * 256 + col0 + c);
            const unsigned short* src;
            if (s < 12) {
                const int kw = ((s & 3) << 6) + ((s >= 8) ? 256 : 0);
                src = gsW2 + grow * 512 + kw + (sl << 3);
            } else {
                src = gsX2 + grow * 64 + (sl << 3);
            }
            glds16(src, &Ws[buf][(w * 48 + (j << 3)) << 6]);
        }
    };

    auto compute = [&](int buf, f32x4 (*tr)[2], f32x4 (*tz)[2], f32x4 (*tn)[2]) {
        #pragma unroll
        for (int kk = 0; kk < 2; ++kk) {
            bf16x8 af[MF], bw[3][2];
            #pragma unroll
            for (int mf = 0; mf < MF; ++mf) {
                const int row = wr * (BM / 2) + (mf << 4) + (lane & 15);
                const int sl = (((kk << 2) | (lane >> 4)) ^ (row & 7)) << 3;
                af[mf] = *(const bf16x8*)&As[buf][(row << 6) + sl];
            }
            #pragma unroll
            for (int g = 0; g < 3; ++g)
                #pragma unroll
                for (int nf = 0; nf < 2; ++nf) {
                    const int R = (g << 6) + (wc << 5) + (nf << 4) + (lane & 15);
                    const int sl = (((kk << 2) | (lane >> 4)) ^ (R & 7)) << 3;
                    bw[g][nf] = *(const bf16x8*)&Ws[buf][(R << 6) + sl];
                }
            __builtin_amdgcn_s_setprio(1);
            #pragma unroll
            for (int mf = 0; mf < MF; ++mf)
                #pragma unroll
                for (int nf = 0; nf < 2; ++nf) {
                    tr[mf][nf] = __builtin_amdgcn_mfma_f32_16x16x32_bf16(af[mf], bw[0][nf], tr[mf][nf], 0, 0, 0);
                    tz[mf][nf] = __builtin_amdgcn_mfma_f32_16x16x32_bf16(af[mf], bw[1][nf], tz[mf][nf], 0, 0, 0);
                    tn[mf][nf] = __builtin_amdgcn_mfma_f32_16x16x32_bf16(af[mf], bw[2][nf], tn[mf][nf], 0, 0, 0);
                }
            __builtin_amdgcn_s_setprio(0);
        }
    };

    stage(0, 0);
    #pragma unroll
    for (int s = 0; s < 13; ++s) {
        if (s + 1 < 13) { stage((s + 1) & 1, s + 1); vmwait<AI + 6>(); }
        else            { vmwait<0>(); }
        sbar();
        if (s < 12) compute(s & 1, a_sr, a_sz, a_snh);
        else        compute(s & 1, a_sr, a_sz, a_snx);
        sbar();
    }

    #pragma unroll
    for (int nf = 0; nf < 2; ++nf) {
        const int jc = col0 + (wc << 5) + (nf << 4) + (lane & 15);
        const float bsr  = gs_bx[jc] + gs_bh[jc];
        const float bsz  = gs_bx[256 + jc] + gs_bh[256 + jc];
        const float bsnx = gs_bx[512 + jc];
        const float bsnh = gs_bh[512 + jc];
        #pragma unroll
        for (int mf = 0; mf < MF; ++mf) {
            #pragma unroll
            for (int r = 0; r < 4; ++r) {
                const int rowl = wr * (BM / 2) + (mf << 4) + ((lane >> 4) << 2) + r;
                const int m = m0 + rowl;
                const float rs = sigmf(a_sr[mf][nf][r] + bsr);
                const float zs = sigmf(a_sz[mf][nf][r] + bsz);
                const float ns = tanhf(a_snx[mf][nf][r] + bsnx + rs * (a_snh[mf][nf][r] + bsnh));
                const size_t hrow = aBase + rowl;
                const float hv = bf2f(Hn2[hrow * 512 + jc]) + bf2f(Hn2[hrow * 512 + 256 + jc]);
                const float val = (1.f - zs) * ns + zs * hv + Apf[(size_t)m * 256 + jc];
                const unsigned short hi = f2bf(val);
                Ap2[(size_t)m * 512 + jc] = hi;
                Ap2[(size_t)m * 512 + 256 + jc] = f2bf(val - bf2f(hi));
            }
        }
    }
}

// ---------------------------------------------------------------------------
extern "C" void kernel_launch(void* const* d_in, const int* in_sizes, int n_in,
                              void* d_out, int out_size, void* d_ws, size_t ws_size,
                              hipStream_t stream) {
    (void)in_sizes; (void)n_in; (void)out_size;

    const float* z      = (const float*)d_in[0];
    const float* h2o_w  = (const float*)d_in[1];
    const float* h2o_b  = (const float*)d_in[2];
    const float* w_c_w  = (const float*)d_in[3];
    const float* w_c_b  = (const float*)d_in[4];
    const float* w_d_w  = (const float*)d_in[5];
    const float* w_d_b  = (const float*)d_in[6];
    const float* z2h1_w = (const float*)d_in[7];
    const float* z2h1_b = (const float*)d_in[8];
    const float* z2h2_w = (const float*)d_in[9];
    const float* z2h2_b = (const float*)d_in[10];
    const float* ga_wx  = (const float*)d_in[11];
    const float* ga_wh  = (const float*)d_in[12];
    const float* ga_bx  = (const float*)d_in[13];
    const float* ga_bh  = (const float*)d_in[14];
    const float* gs_wx  = (const float*)d_in[15];
    const float* gs_wh  = (const float*)d_in[16];
    const float* gs_bx  = (const float*)d_in[17];
    const float* gs_bh  = (const float*)d_in[18];

    float* out = (float*)d_out;

    size_t off = 0;
    auto alloc = [&](size_t bytes) -> void* {
        void* r = (char*)d_ws + off;
        off += (bytes + 255) & ~(size_t)255;
        return r;
    };
    unsigned short* H2a  = (unsigned short*)alloc(16ull * 1024 * 512 * 2);
    unsigned short* H2b  = (unsigned short*)alloc(32ull * 1024 * 512 * 2);
    unsigned short* SP2a = (unsigned short*)alloc(16ull * 1024 * 64 * 2);
    unsigned short* SP2b = (unsigned short*)alloc(32ull * 1024 * 64 * 2);
    float* hacF0 = (float*)alloc(1024ull * 256 * 4);
    float* hacF1 = (float*)alloc(1024ull * 256 * 4);
    unsigned short* hac20 = (unsigned short*)alloc(1024ull * 512 * 2);
    unsigned short* hac21 = (unsigned short*)alloc(1024ull * 512 * 2);
    float* GhA = (float*)alloc(1024ull * 768 * 4);
    float* Apf = (float*)alloc(16ull * 1024 * 256 * 4);
    unsigned short* Ap2 = (unsigned short*)alloc(16ull * 1024 * 512 * 2);
    unsigned short* z2  = (unsigned short*)alloc(1024ull * 512 * 2);
    unsigned short* wd2 = (unsigned short*)alloc(256ull * 512 * 2);
    unsigned short* wc2 = (unsigned short*)alloc(256ull * 512 * 2);
    unsigned short* z12 = (unsigned short*)alloc(256ull * 512 * 2);
    unsigned short* z22 = (unsigned short*)alloc(256ull * 512 * 2);
    unsigned short* gaW2 = (unsigned short*)alloc(768ull * 512 * 2);
    unsigned short* gsW2 = (unsigned short*)alloc(768ull * 512 * 2);
    unsigned short* gsX2 = (unsigned short*)alloc(768ull * 64 * 2);
    if (off > ws_size) return;  // tripwire: output stays poisoned -> visible fail

    const dim3 blk(256);

    CvtArgs ca = {{
        { z,      z2,   1024 * 256, 8 },
        { w_d_w,  wd2,  256 * 256,  8 },
        { w_c_w,  wc2,  256 * 256,  8 },
        { z2h1_w, z12,  256 * 256,  8 },
        { z2h2_w, z22,  256 * 256,  8 },
        { ga_wh,  gaW2, 768 * 256,  8 },
        { gs_wh,  gsW2, 768 * 256,  8 },
        { gs_wx,  gsX2, 768 * 32,   5 },
    }};
    cvt_bf16x2<<<dim3(64, 8), blk, 0, stream>>>(ca);

    // init: hac = z@z2h1^T+b ; H(root) = z@z2h2^T+b ; root pred+softmax
    mfma_gemm<64><<<dim3(16, 2), blk, 0, stream>>>(z2, z12, z2h1_b, hacF0, 256, hac20, 1, 0);
    mfma_gemm<64><<<dim3(16, 2), blk, 0, stream>>>(z2, z22, z2h2_b, nullptr, 0, H2a, 1, 0);
    pred_softmax<<<dim3(128), blk, 0, stream>>>(H2a, h2o_w, h2o_b, out, SP2a, 0, 1, 0);

    unsigned short* cur2 = H2a;  unsigned short* nxt2 = H2b;
    unsigned short* spc  = SP2a; unsigned short* spn  = SP2b;
    float* hf = hacF0;  float* hn = hacF1;
    unsigned short* hf2 = hac20; unsigned short* hn2 = hac21;

    for (int l = 0; l < DEPTHC - 1; ++l) {
        const int M = (1 << l) * Bdim;
        const bool small = (M <= 8192);

        // first children: H' = lin_d(H) -> slots 2p
        if (small) mfma_gemm<64><<<dim3(M / 64, 2), blk, 0, stream>>>(cur2, wd2, w_d_b, nullptr, 0, nxt2, 2, 0);
        else       mfma_gemm<128><<<dim3(M / 128, 2), blk, 0, stream>>>(cur2, wd2, w_d_b, nullptr, 0, nxt2, 2, 0);
        // pred + softmax of first children
        pred_softmax<<<dim3(M / 8), blk, 0, stream>>>(nxt2, h2o_w, h2o_b, out, spn, l + 1, 2, 0);
        // shared ancestral gate h-part: GhA = hac @ ga_wh^T + ga_bh  [1024 x 768]
        mfma_gemm<64><<<dim3(16, 6), blk, 0, stream>>>(hf2, gaW2, ga_bh, GhA, 768, nullptr, 1, 0);
        // ancestral GRU: Apf = gru_a(sp_parent, hac)
        gru_a_kernel<<<dim3(M / 16), blk, 0, stream>>>(spc, GhA, ga_wx, ga_bx, hf, Apf);
        // fraternal GRU on first children + combine -> hidden2 (bf16x2) in Ap2
        if (small) gru_s_fused<64><<<dim3(M / 64, 4), blk, 0, stream>>>(nxt2, spn, gsW2, gsX2, gs_bx, gs_bh, Apf, Ap2);
        else       gru_s_fused<128><<<dim3(M / 128, 4), blk, 0, stream>>>(nxt2, spn, gsW2, gsX2, gs_bx, gs_bh, Apf, Ap2);
        // second children: H'' = lin_d(hidden2) -> slots 2p+1
        if (small) mfma_gemm<64><<<dim3(M / 64, 2), blk, 0, stream>>>(Ap2, wd2, w_d_b, nullptr, 0, nxt2, 2, 1);
        else       mfma_gemm<128><<<dim3(M / 128, 2), blk, 0, stream>>>(Ap2, wd2, w_d_b, nullptr, 0, nxt2, 2, 1);
        // pred + softmax of second children
        pred_softmax<<<dim3(M / 8), blk, 0, stream>>>(nxt2, h2o_w, h2o_b, out, spn, l + 1, 2, 1);
        // next-level shared ancestral hidden: hac' = lin_c(hac)
        mfma_gemm<64><<<dim3(16, 2), blk, 0, stream>>>(hf2, wc2, w_c_b, hn, 256, hn2, 1, 0);

        // swap ping-pong buffers
        unsigned short* t2;
        t2 = cur2; cur2 = nxt2; nxt2 = t2;
        t2 = spc;  spc  = spn;  spn  = t2;
        float* tf = hf; hf = hn; hn = tf;
        t2 = hf2; hf2 = hn2; hn2 = t2;
    }
}